// Round 6
// baseline (1300.818 us; speedup 1.0000x reference)
//
#include <hip/hip_runtime.h>
#include <math.h>

// ---------------- problem constants ----------------
constexpr int NND = 4096;     // nodes
constexpr int EDG = 32768;    // edges
constexpr float SQRT3  = 1.7320508075688772f;
constexpr float ISQRT3 = 0.5773502691896258f;
constexpr float NORMI  = 1.0f / 32767.0f;   // 1/(E-1)

__device__ __forceinline__ float gelu_f(float x) {
    float x3 = x * x * x;
    return 0.5f * x * (1.0f + tanhf(0.7978845608028654f * (x + 0.044715f * x3)));
}
__device__ __forceinline__ float sigmoid_f(float x) {
    return 1.0f / (1.0f + expf(-x));
}

// ---------------- CSR construction (once per launch) ----------------
__global__ __launch_bounds__(256)
void segnn_deg_kernel(const int* __restrict__ rcv, int* __restrict__ deg) {
    const int e = blockIdx.x * 256 + threadIdx.x;
    if (e < EDG) atomicAdd(deg + rcv[e], 1);
}

__global__ __launch_bounds__(1024)
void segnn_scan_kernel(const int* __restrict__ deg, int* __restrict__ off) {
    __shared__ int tots[1024];
    const int t = threadIdx.x;
    const int v0 = deg[4*t], v1 = deg[4*t+1], v2 = deg[4*t+2], v3 = deg[4*t+3];
    const int p1 = v0, p2 = p1 + v1, p3 = p2 + v2, p4 = p3 + v3;
    tots[t] = p4;
    __syncthreads();
    for (int d = 1; d < 1024; d <<= 1) {
        const int add = (t >= d) ? tots[t - d] : 0;
        __syncthreads();
        tots[t] += add;
        __syncthreads();
    }
    const int excl = t ? tots[t-1] : 0;
    off[4*t+0] = excl;
    off[4*t+1] = excl + p1;
    off[4*t+2] = excl + p2;
    off[4*t+3] = excl + p3;
    if (t == 1023) off[4096] = tots[1023];
}

__global__ __launch_bounds__(256)
void segnn_scatter_kernel(const int* __restrict__ rcv, const int* __restrict__ off,
                          int* __restrict__ cursor, int* __restrict__ elist) {
    const int e = blockIdx.x * 256 + threadIdx.x;
    if (e < EDG) {
        const int j = rcv[e];
        const int p = atomicAdd(cursor + j, 1);
        elist[off[j] + p] = e;
    }
}

// ---------------- fused edge pipeline: wave-autonomous, 8 edges/wave ----------------
// Each 64-lane wave owns 8 edges end-to-end. No __syncthreads anywhere.
// Pass A: 16 col-slots x 4 K-groups; acc[8 edges][6 cols] in regs; shuffle-reduce.
// Pass B: 16 cols x 4 K-groups over vector rows.
template<int NSX, int NVX>
__device__ __forceinline__ void edge_phase_w(
    const int lane,
    const float* __restrict__ Ws, const float* __restrict__ Bs,
    const float* __restrict__ Wv,
    float (*xt)[10], float (*x2)[10], float (*cb)[96], float (*cvv)[48])
{
    const int cs = lane & 15, kg = lane >> 4;
    constexpr int KA = NSX + NVX;
    constexpr int CH = KA / 4;

    // ---- pass A ----
    {
        float acc[8][6];
#pragma unroll
        for (int j = 0; j < 8; ++j)
#pragma unroll
            for (int c = 0; c < 6; ++c) acc[j][c] = 0.0f;
        const int r0 = kg * CH;
#pragma unroll 4
        for (int rr = 0; rr < CH; ++rr) {
            const int r = r0 + rr;
            const float* wp = Ws + r*80 + cs;
            const float w0 = wp[0], w1 = wp[16], w2 = wp[32], w3 = wp[48], w4 = wp[64];
            const float w5 = (r < NSX) ? Wv[r*16 + cs] : 0.0f;
            const float2 xa = *reinterpret_cast<const float2*>(&xt[r][0]);
            const float2 xb = *reinterpret_cast<const float2*>(&xt[r][2]);
            const float2 xc = *reinterpret_cast<const float2*>(&xt[r][4]);
            const float2 xd = *reinterpret_cast<const float2*>(&xt[r][6]);
            const float xe[8] = { xa.x,xa.y, xb.x,xb.y, xc.x,xc.y, xd.x,xd.y };
#pragma unroll
            for (int j = 0; j < 8; ++j) {
                acc[j][0] = fmaf(xe[j], w0, acc[j][0]);
                acc[j][1] = fmaf(xe[j], w1, acc[j][1]);
                acc[j][2] = fmaf(xe[j], w2, acc[j][2]);
                acc[j][3] = fmaf(xe[j], w3, acc[j][3]);
                acc[j][4] = fmaf(xe[j], w4, acc[j][4]);
                acc[j][5] = fmaf(xe[j], w5, acc[j][5]);
            }
        }
#pragma unroll
        for (int j = 0; j < 8; ++j)
#pragma unroll
            for (int c = 0; c < 6; ++c) {
                float a = acc[j][c];
                a += __shfl_xor(a, 16);
                a += __shfl_xor(a, 32);
                acc[j][c] = a;
            }
        if (lane < 16) {
#pragma unroll
            for (int j = 0; j < 8; ++j) {
#pragma unroll
                for (int c = 0; c < 5; ++c) cb[j][cs + 16*c] = acc[j][c] + Bs[cs + 16*c];
                cb[j][80 + cs] = acc[j][5];
            }
        }
    }

    // ---- pass B (identity-path vector outputs) ----
    {
        constexpr int CHB = NVX / 4;
        float av[8][3];
#pragma unroll
        for (int j = 0; j < 8; ++j) { av[j][0]=0.0f; av[j][1]=0.0f; av[j][2]=0.0f; }
        const int m0 = kg * CHB;
#pragma unroll
        for (int mm = 0; mm < CHB; ++mm) {
            const int m = m0 + mm;
            const float w = Wv[(NSX + m)*16 + cs];
#pragma unroll
            for (int d = 0; d < 3; ++d) {
                const float2 xa = *reinterpret_cast<const float2*>(&x2[d*NVX + m][0]);
                const float2 xb = *reinterpret_cast<const float2*>(&x2[d*NVX + m][2]);
                const float2 xc = *reinterpret_cast<const float2*>(&x2[d*NVX + m][4]);
                const float2 xd = *reinterpret_cast<const float2*>(&x2[d*NVX + m][6]);
                const float xe[8] = { xa.x,xa.y, xb.x,xb.y, xc.x,xc.y, xd.x,xd.y };
#pragma unroll
                for (int j = 0; j < 8; ++j) av[j][d] = fmaf(xe[j], w, av[j][d]);
            }
        }
#pragma unroll
        for (int j = 0; j < 8; ++j)
#pragma unroll
            for (int d = 0; d < 3; ++d) {
                float a = av[j][d];
                a += __shfl_xor(a, 16);
                a += __shfl_xor(a, 32);
                av[j][d] = a;
            }
        if (lane < 16) {
#pragma unroll
            for (int j = 0; j < 8; ++j)
#pragma unroll
                for (int d = 0; d < 3; ++d) cvv[j][cs*3 + d] = av[j][d];
        }
    }
    asm volatile("" ::: "memory");
}

__global__ __launch_bounds__(256, 2)
void segnn_edge_fused(const float* __restrict__ cs, const float* __restrict__ cv,
                      const int* __restrict__ snd, const int* __restrict__ rcv,
                      const float* __restrict__ W0s, const float* __restrict__ B0, const float* __restrict__ W0v,
                      const float* __restrict__ W1s, const float* __restrict__ B1, const float* __restrict__ W1v,
                      const float* __restrict__ W2s, const float* __restrict__ B2, const float* __restrict__ W2v,
                      float* __restrict__ msg) {
    __shared__ __align__(16) float XT [4][160][10];  // per-wave transposed scalar|dot rows
    __shared__ __align__(16) float X2T[4][96][10];   // per-wave vector-component rows
    __shared__ __align__(16) float Cb [4][8][96];    // per-wave pass-A outputs
    __shared__ __align__(16) float Cv [4][8][48];    // per-wave pass-B outputs
    __shared__ float UU [4][8][4];

    const int tid  = threadIdx.x;
    const int w    = tid >> 6;
    const int lane = tid & 63;
    const int e0   = blockIdx.x * 32 + w * 8;

    float (*xt)[10]  = XT[w];
    float (*x2)[10]  = X2T[w];
    float (*cb)[96]  = Cb[w];
    float (*cvv)[48] = Cv[w];
    float (*uuw)[4]  = UU[w];

    // ---- staging: scalars (rows 0..127 = s_i | s_j) ----
#pragma unroll
    for (int it = 0; it < 16; ++it) {
        const int e = it >> 1, half = it & 1;
        const int node = (half ? rcv : snd)[e0 + e];
        xt[half*64 + lane][e] = cs[(size_t)node*64 + lane];
    }
    // ---- staging: vectors -> X2T rows d*32 + part*16 + m ----
#pragma unroll
    for (int it = 0; it < 16; ++it) {
        const int e = it >> 1, half = it & 1;
        if (lane < 48) {
            const int node = (half ? rcv : snd)[e0 + e];
            const int m = lane / 3, d = lane - 3*m;
            x2[d*32 + half*16 + m][e] = cv[(size_t)node*48 + lane];
        }
    }
    asm volatile("" ::: "memory");
    if (lane < 8) {
        const float rx = x2[0][lane]  - x2[16][lane];
        const float ry = x2[32][lane] - x2[48][lane];
        const float rz = x2[64][lane] - x2[80][lane];
        const float rinv = 1.0f / fmaxf(sqrtf(rx*rx+ry*ry+rz*rz), 1e-9f);
        uuw[lane][0] = rx*rinv; uuw[lane][1] = ry*rinv; uuw[lane][2] = rz*rinv;
    }
    asm volatile("" ::: "memory");
    // dot rows 128..159: v_m . u
#pragma unroll
    for (int it = 0; it < 4; ++it) {
        const int idx = it*64 + lane;
        const int e = idx >> 5, mm = idx & 31;
        xt[128 + mm][e] = x2[mm][e]*uuw[e][0] + x2[32+mm][e]*uuw[e][1] + x2[64+mm][e]*uuw[e][2];
    }
    asm volatile("" ::: "memory");

    // ---- phase 0 ----
    edge_phase_w<128,32>(lane, W0s, B0, W0v, xt, x2, cb, cvv);
    // activation -> next XT (64 scalar + 16 dot), X2T (48 rows)
#pragma unroll
    for (int it = 0; it < 8; ++it) {
        xt[lane][it] = gelu_f(cb[it][lane]);
    }
#pragma unroll
    for (int it = 0; it < 2; ++it) {
        const int idx = it*64 + lane;
        const int e = idx >> 4, o = idx & 15;
        const float g = sigmoid_f(cb[e][64+o]);
        const float t = cb[e][80+o] * SQRT3;
        float p = 0.0f;
#pragma unroll
        for (int d = 0; d < 3; ++d) {
            const float vd = fmaf(t, uuw[e][d], cvv[e][o*3+d]) * g;
            x2[d*16 + o][e] = vd;
            p = fmaf(vd, uuw[e][d], p);
        }
        xt[64 + o][e] = p;
    }
    asm volatile("" ::: "memory");

    // ---- phase 1 ----
    edge_phase_w<64,16>(lane, W1s, B1, W1v, xt, x2, cb, cvv);
#pragma unroll
    for (int it = 0; it < 8; ++it) {
        xt[lane][it] = gelu_f(cb[it][lane]);
    }
#pragma unroll
    for (int it = 0; it < 2; ++it) {
        const int idx = it*64 + lane;
        const int e = idx >> 4, o = idx & 15;
        const float g = sigmoid_f(cb[e][64+o]);
        const float t = cb[e][80+o] * SQRT3;
        float p = 0.0f;
#pragma unroll
        for (int d = 0; d < 3; ++d) {
            const float vd = fmaf(t, uuw[e][d], cvv[e][o*3+d]) * g;
            x2[d*16 + o][e] = vd;
            p = fmaf(vd, uuw[e][d], p);
        }
        xt[64 + o][e] = p;
    }
    asm volatile("" ::: "memory");

    // ---- phase 2 + coalesced message write ----
    edge_phase_w<64,16>(lane, W2s, B2, W2v, xt, x2, cb, cvv);
#pragma unroll
    for (int it = 0; it < 15; ++it) {
        const int idx = it*64 + lane;
        if (idx < 920) {
            const int e = idx / 115, f = idx - 115*e;
            float vv;
            if (f < 64) {
                vv = gelu_f(cb[e][f]);
            } else if (f < 112) {
                const int q = f - 64, o = q / 3, d = q - 3*o;
                const float g = sigmoid_f(cb[e][64+o]);
                vv = fmaf(cb[e][80+o] * SQRT3, uuw[e][d], cvv[e][q]) * g;
            } else {
                vv = uuw[e][f-112];
            }
            msg[(size_t)(e0+e)*116 + f] = vv;
        }
    }
}

// ---------------- gather: CSR segment-mean -> y ----------------
__global__ __launch_bounds__(128)
void segnn_gather_kernel(const float* __restrict__ msg, const int* __restrict__ off,
                         const int* __restrict__ elist,
                         float* __restrict__ y_s, float* __restrict__ y_v) {
    const int n = blockIdx.x, f = threadIdx.x;
    const int o0 = off[n], o1 = off[n+1];
    const int deg = o1 - o0;
    float acc = 0.0f;
    for (int p = o0; p < o1; ++p) {
        const int eid = elist[p];
        if (f < 115) acc += msg[(size_t)eid*116 + f];
    }
    const float inv = NORMI / (float)(deg > 0 ? deg : 1);
    if (f < 64)        y_s[(size_t)n*65 + f] = acc * inv;
    else if (f < 112)  y_v[(size_t)n*51 + (f-64)] = acc * inv;
    else if (f < 115)  y_v[(size_t)n*51 + 48 + (f-112)] = SQRT3 * acc * inv;
    else if (f == 115) y_s[(size_t)n*65 + 64] = deg ? NORMI : 0.0f;
}

// ---------------- node TP-gate block: GEMM, W reg-pipelined, raw barriers ----------------
__global__ __launch_bounds__(512, 2)
void segnn_node_kernel(const float* __restrict__ in_s, const float* __restrict__ in_v,
                       const float* __restrict__ y_s, const float* __restrict__ y_v,
                       const float* __restrict__ W,  const float* __restrict__ B,
                       const float* __restrict__ Wv,
                       float* __restrict__ out_s, float* __restrict__ out_v) {
    __shared__ __align__(16) float xsL[8*65];
    __shared__ __align__(16) float ysL[8*65];
    __shared__ __align__(16) float xvL[8*49];
    __shared__ __align__(16) float yvL[8*51];
    __shared__ __align__(16) float Xa[2][3072];
    __shared__ __align__(16) float red[8][16][41];
    __shared__ float finGG[8*16];

    const int tid  = threadIdx.x;
    const int lane = tid & 63;
    const int wv   = tid >> 6;
    const int nb0  = blockIdx.x * 8;

    for (int idx = tid; idx < 8*64; idx += 512) { const int n = idx >> 6, m = idx & 63; xsL[n*65+m] = in_s[(size_t)(nb0+n)*64 + m]; }
    for (int idx = tid; idx < 8*65; idx += 512) { const int n = idx / 65, k = idx - n*65; ysL[n*65+k] = y_s[(size_t)(nb0+n)*65 + k]; }
    for (int idx = tid; idx < 8*48; idx += 512) { const int n = idx / 48, m = idx - n*48; xvL[n*49+m] = in_v[(size_t)(nb0+n)*48 + m]; }
    for (int idx = tid; idx < 8*51; idx += 512) { const int n = idx / 51, m = idx - n*51; yvL[n*51+m] = y_v[(size_t)(nb0+n)*51 + m]; }
    __syncthreads();

    // ================= ss GEMM =================
    {
        const int cs = tid & 15;
        const int rowgrp = tid >> 4;

        float acc[8][5];
#pragma unroll
        for (int n = 0; n < 8; ++n)
#pragma unroll
            for (int c = 0; c < 5; ++c) acc[n][c] = 0.0f;

        auto genS = [&](int t, int b) {
            const int base = t * 128;
#pragma unroll
            for (int ii = 0; ii < 2; ++ii) {
                const int idx = tid + ii*512;
                const int rl = idx >> 3, n = idx & 7;
                const int r = base + rl;
                float val = 0.0f;
                if (r < 4160) {
                    const int m = r / 65, k = r - m*65;
                    val = xsL[n*65+m] * ysL[n*65+k];
                } else if (r < 4432) {
                    const int q = r - 4160;
                    const int m = q / 17, k = q - m*17;
                    val = (xvL[n*49+m*3+0]*yvL[n*51+k*3+0] +
                           xvL[n*49+m*3+1]*yvL[n*51+k*3+1] +
                           xvL[n*49+m*3+2]*yvL[n*51+k*3+2]) * ISQRT3;
                }
                Xa[b][idx] = val;
            }
        };
        auto loadW = [&](int t, float wreg[4][5]) {
            const int base = t * 128;
#pragma unroll
            for (int v2 = 0; v2 < 4; ++v2) {
                const int r = base + rowgrp + 32*v2;
                const int wr = r < 4431 ? r : 4431;
                const float* wp = W + (size_t)wr * 80 + cs;
                wreg[v2][0] = wp[0];  wreg[v2][1] = wp[16]; wreg[v2][2] = wp[32];
                wreg[v2][3] = wp[48]; wreg[v2][4] = wp[64];
            }
        };

        float wc[4][5], wn[4][5];
        loadW(0, wc);
        genS(0, 0);
        asm volatile("s_waitcnt lgkmcnt(0)" ::: "memory");
        __builtin_amdgcn_s_barrier();
        asm volatile("" ::: "memory");
        for (int t = 0; t < 35; ++t) {
            if (t + 1 < 35) { loadW(t + 1, wn); genS(t + 1, (t + 1) & 1); }
            const float* Xb = &Xa[t & 1][0];
#pragma unroll
            for (int v2 = 0; v2 < 4; ++v2) {
                const int rl = rowgrp + 32*v2;
                const float4 xq0 = *reinterpret_cast<const float4*>(&Xb[rl*8]);
                const float4 xq1 = *reinterpret_cast<const float4*>(&Xb[rl*8+4]);
                const float xn[8] = { xq0.x, xq0.y, xq0.z, xq0.w, xq1.x, xq1.y, xq1.z, xq1.w };
#pragma unroll
                for (int n = 0; n < 8; ++n) {
                    acc[n][0] = fmaf(xn[n], wc[v2][0], acc[n][0]);
                    acc[n][1] = fmaf(xn[n], wc[v2][1], acc[n][1]);
                    acc[n][2] = fmaf(xn[n], wc[v2][2], acc[n][2]);
                    acc[n][3] = fmaf(xn[n], wc[v2][3], acc[n][3]);
                    acc[n][4] = fmaf(xn[n], wc[v2][4], acc[n][4]);
                }
            }
            asm volatile("s_waitcnt lgkmcnt(0)" ::: "memory");
            __builtin_amdgcn_s_barrier();
            asm volatile("" ::: "memory");
#pragma unroll
            for (int v2 = 0; v2 < 4; ++v2)
#pragma unroll
                for (int c = 0; c < 5; ++c) wc[v2][c] = wn[v2][c];
        }

#pragma unroll
        for (int n = 0; n < 8; ++n)
#pragma unroll
            for (int c = 0; c < 5; ++c) {
                float a = acc[n][c];
                a += __shfl_xor(a, 16);
                a += __shfl_xor(a, 32);
                if (lane < 16) red[wv][lane][n*5+c] = a;
            }
        __syncthreads();
        for (int idx = tid; idx < 8*80; idx += 512) {
            const int n = idx / 80, col = idx - n*80;
            const int cs2 = col & 15, ci2 = col >> 4;
            float s = B[col];
#pragma unroll
            for (int ww = 0; ww < 8; ++ww) s += red[ww][cs2][n*5+ci2];
            if (col < 64) out_s[(size_t)(nb0+n)*64 + col] = gelu_f(s);
            else          finGG[n*16 + (col-64)] = s;
        }
        __syncthreads();
    }

    // ================= vec GEMM =================
    {
        const int j4 = tid & 3;
        const int ngrp = (tid >> 2) & 1;
        const int rg = tid >> 3;

        float av[12][4];
#pragma unroll
        for (int a = 0; a < 12; ++a)
#pragma unroll
            for (int c = 0; c < 4; ++c) av[a][c] = 0.0f;

        auto genV = [&](int t, int b) {
            const int base = t * 128;
#pragma unroll
            for (int ii = 0; ii < 6; ++ii) {
                const int idx = tid + ii*512;
                const int rl = idx / 24, ar = idx - rl*24;
                const int n = ar / 3, d = ar - n*3;
                const int r = base + rl;
                float val = 0.0f;
                if (r < 1088) {
                    const int m = r / 17, k = r - m*17;
                    val = xsL[n*65+m] * yvL[n*51+k*3+d];
                } else if (r < 2128) {
                    const int q = r - 1088;
                    const int m = q / 65, k = q - m*65;
                    val = xvL[n*49+m*3+d] * ysL[n*65+k];
                }
                Xa[b][idx] = val;
            }
        };
        auto loadWv = [&](int t, float4 wreg[2]) {
#pragma unroll
            for (int v2 = 0; v2 < 2; ++v2) {
                const int r = t*128 + rg + 64*v2;
                const int wr = r < 2127 ? r : 2127;
                wreg[v2] = *reinterpret_cast<const float4*>(&Wv[(size_t)wr*16 + 4*j4]);
            }
        };

        float4 wqc[2], wqn[2];
        loadWv(0, wqc);
        genV(0, 0);
        asm volatile("s_waitcnt lgkmcnt(0)" ::: "memory");
        __builtin_amdgcn_s_barrier();
        asm volatile("" ::: "memory");
        for (int t = 0; t < 17; ++t) {
            if (t + 1 < 17) { loadWv(t + 1, wqn); genV(t + 1, (t + 1) & 1); }
            const float* Xb = &Xa[t & 1][0];
#pragma unroll
            for (int v2 = 0; v2 < 2; ++v2) {
                const int rl = rg + 64*v2;
                const float4 w4 = wqc[v2];
                const float4 xq0 = *reinterpret_cast<const float4*>(&Xb[rl*24 + 12*ngrp]);
                const float4 xq1 = *reinterpret_cast<const float4*>(&Xb[rl*24 + 12*ngrp + 4]);
                const float4 xq2 = *reinterpret_cast<const float4*>(&Xb[rl*24 + 12*ngrp + 8]);
                const float xr[12] = { xq0.x,xq0.y,xq0.z,xq0.w, xq1.x,xq1.y,xq1.z,xq1.w, xq2.x,xq2.y,xq2.z,xq2.w };
#pragma unroll
                for (int a = 0; a < 12; ++a) {
                    av[a][0] = fmaf(xr[a], w4.x, av[a][0]);
                    av[a][1] = fmaf(xr[a], w4.y, av[a][1]);
                    av[a][2] = fmaf(xr[a], w4.z, av[a][2]);
                    av[a][3] = fmaf(xr[a], w4.w, av[a][3]);
                }
            }
            asm volatile("s_waitcnt lgkmcnt(0)" ::: "memory");
            __builtin_amdgcn_s_barrier();
            asm volatile("" ::: "memory");
            wqc[0] = wqn[0]; wqc[1] = wqn[1];
        }

        float* redf = &red[0][0][0];
#pragma unroll
        for (int a = 0; a < 12; ++a)
#pragma unroll
            for (int c = 0; c < 4; ++c) {
                float x = av[a][c];
                x += __shfl_xor(x, 8);
                x += __shfl_xor(x, 16);
                x += __shfl_xor(x, 32);
                if (lane < 8) redf[wv*392 + lane*49 + a*4 + c] = x;
            }
        __syncthreads();
        for (int idx = tid; idx < 24*16; idx += 512) {
            const int ar = idx >> 4, j = idx & 15;
            const int n = ar / 3, d = ar - n*3;
            const int ng2 = ar / 12, a2 = ar - 12*ng2;
            const int jj4 = j >> 2, c2 = j & 3;
            float s = 0.0f;
#pragma unroll
            for (int ww = 0; ww < 8; ++ww) s += redf[ww*392 + (jj4 + 4*ng2)*49 + a2*4 + c2];
            out_v[(size_t)(nb0+n)*48 + j*3 + d] = s * sigmoid_f(finGG[n*16 + j]);
        }
    }
}

// ---------------- per-step final Linear ----------------
__global__ __launch_bounds__(256)
void segnn_linear_kernel(const float* __restrict__ in_s, const float* __restrict__ in_v,
                         const float* __restrict__ lws, const float* __restrict__ lb,
                         const float* __restrict__ lwv,
                         float* __restrict__ out_s, float* __restrict__ out_v,
                         float* __restrict__ out_cat) {
    const int idx = blockIdx.x * 256 + threadIdx.x;
    if (idx >= NND * 112) return;
    const int nidx = idx / 112, f = idx - nidx * 112;
    if (f < 48) {
        const int k = f / 3, d = f - 3*k;
        const float* vp = in_v + (size_t)nidx * 48 + d;
        float acc = 0.0f;
#pragma unroll
        for (int m = 0; m < 16; ++m) acc = fmaf(vp[m*3], lwv[m*16 + k], acc);
        if (out_cat) out_cat[(size_t)nidx*112 + f] = acc;
        else         out_v[(size_t)nidx*48 + f] = acc;
    } else {
        const int o = f - 48;
        const float* sp = in_s + (size_t)nidx * 64;
        float acc = lb[o];
#pragma unroll
        for (int m = 0; m < 64; ++m) acc = fmaf(sp[m], lws[m*64 + o], acc);
        if (out_cat) out_cat[(size_t)nidx*112 + f] = acc;
        else         out_s[(size_t)nidx*64 + o] = acc;
    }
}

// ---------------- host launcher ----------------
extern "C" void kernel_launch(void* const* d_in, const int* in_sizes, int n_in,
                              void* d_out, int out_size, void* d_ws, size_t ws_size,
                              hipStream_t stream) {
    const float* in_s  = (const float*)d_in[0];
    const float* in_v  = (const float*)d_in[1];
    const int*   snd   = (const int*)  d_in[2];
    const int*   rcv   = (const int*)  d_in[3];
    const float* e1_ws = (const float*)d_in[4];
    const float* e1_b  = (const float*)d_in[5];
    const float* e1_wv = (const float*)d_in[6];
    const float* e2_ws = (const float*)d_in[7];
    const float* e2_b  = (const float*)d_in[8];
    const float* e2_wv = (const float*)d_in[9];
    const float* n_ws  = (const float*)d_in[10];
    const float* n_b   = (const float*)d_in[11];
    const float* n_wv  = (const float*)d_in[12];
    const float* l_ws  = (const float*)d_in[13];
    const float* l_b   = (const float*)d_in[14];
    const float* l_wv  = (const float*)d_in[15];

    float* ws    = (float*)d_ws;
    float* cur_s = ws;                           // N*64   = 262144
    float* cur_v = cur_s + 262144;               // N*48   = 196608
    float* nxt_s = cur_v + 196608;               // N*64
    float* nxt_v = nxt_s + 262144;               // N*48
    float* y_s   = nxt_v + 196608;               // N*65   = 266240
    float* y_v   = y_s + 266240;                 // N*51   = 208896
    float* msg   = y_v + 208896;                 // E*116  = 3801088
    int*   deg    = (int*)(msg + 3801088);       // N
    int*   cursor = deg + 4096;                  // N
    int*   off    = cursor + 4096;               // N+1
    int*   elist  = off + 4097;                  // E

    hipMemsetAsync(deg, 0, (size_t)8192 * sizeof(int), stream);
    hipMemcpyAsync(cur_s, in_s, (size_t)262144 * sizeof(float), hipMemcpyDeviceToDevice, stream);
    hipMemcpyAsync(cur_v, in_v, (size_t)196608 * sizeof(float), hipMemcpyDeviceToDevice, stream);
    segnn_deg_kernel<<<EDG/256, 256, 0, stream>>>(rcv, deg);
    segnn_scan_kernel<<<1, 1024, 0, stream>>>(deg, off);
    segnn_scatter_kernel<<<EDG/256, 256, 0, stream>>>(rcv, off, cursor, elist);

    for (int step = 0; step < 3; ++step) {
        segnn_edge_fused<<<EDG/32, 256, 0, stream>>>(cur_s, cur_v, snd, rcv,
            e1_ws + (size_t)step*160*80, e1_b + step*80, e1_wv + (size_t)step*160*16,
            e2_ws + (size_t)(step*2+0)*80*80, e2_b + (step*2+0)*80, e2_wv + (size_t)(step*2+0)*80*16,
            e2_ws + (size_t)(step*2+1)*80*80, e2_b + (step*2+1)*80, e2_wv + (size_t)(step*2+1)*80*16,
            msg);
        segnn_gather_kernel<<<NND, 128, 0, stream>>>(msg, off, elist, y_s, y_v);

        segnn_node_kernel<<<NND/8, 512, 0, stream>>>(cur_s, cur_v, y_s, y_v,
            n_ws + (size_t)(step*3+0)*4432*80, n_b + (step*3+0)*80, n_wv + (size_t)(step*3+0)*2128*16,
            nxt_s, nxt_v);
        segnn_node_kernel<<<NND/8, 512, 0, stream>>>(nxt_s, nxt_v, y_s, y_v,
            n_ws + (size_t)(step*3+1)*4432*80, n_b + (step*3+1)*80, n_wv + (size_t)(step*3+1)*2128*16,
            cur_s, cur_v);
        segnn_node_kernel<<<NND/8, 512, 0, stream>>>(cur_s, cur_v, y_s, y_v,
            n_ws + (size_t)(step*3+2)*4432*80, n_b + (step*3+2)*80, n_wv + (size_t)(step*3+2)*2128*16,
            nxt_s, nxt_v);

        segnn_linear_kernel<<<(NND*112 + 255)/256, 256, 0, stream>>>(nxt_s, nxt_v,
            l_ws + (size_t)step*64*64, l_b + step*64, l_wv + (size_t)step*16*16,
            cur_s, cur_v, (step == 2) ? (float*)d_out : nullptr);
    }
}

// Round 7
// 1065.072 us; speedup vs baseline: 1.2213x; 1.2213x over previous
//
#include <hip/hip_runtime.h>
#include <math.h>

// ---------------- problem constants ----------------
constexpr int NND = 4096;     // nodes
constexpr int EDG = 32768;    // edges
constexpr float SQRT3  = 1.7320508075688772f;
constexpr float ISQRT3 = 0.5773502691896258f;
constexpr float NORMI  = 1.0f / 32767.0f;   // 1/(E-1)

__device__ __forceinline__ float gelu_f(float x) {
    float x3 = x * x * x;
    return 0.5f * x * (1.0f + tanhf(0.7978845608028654f * (x + 0.044715f * x3)));
}
__device__ __forceinline__ float sigmoid_f(float x) {
    return 1.0f / (1.0f + expf(-x));
}

// ---------------- CSR construction (once per launch) ----------------
__global__ __launch_bounds__(256)
void segnn_deg_kernel(const int* __restrict__ rcv, int* __restrict__ deg) {
    const int e = blockIdx.x * 256 + threadIdx.x;
    if (e < EDG) atomicAdd(deg + rcv[e], 1);
}

__global__ __launch_bounds__(1024)
void segnn_scan_kernel(const int* __restrict__ deg, int* __restrict__ off) {
    __shared__ int tots[1024];
    const int t = threadIdx.x;
    const int v0 = deg[4*t], v1 = deg[4*t+1], v2 = deg[4*t+2], v3 = deg[4*t+3];
    const int p1 = v0, p2 = p1 + v1, p3 = p2 + v2, p4 = p3 + v3;
    tots[t] = p4;
    __syncthreads();
    for (int d = 1; d < 1024; d <<= 1) {
        const int add = (t >= d) ? tots[t - d] : 0;
        __syncthreads();
        tots[t] += add;
        __syncthreads();
    }
    const int excl = t ? tots[t-1] : 0;
    off[4*t+0] = excl;
    off[4*t+1] = excl + p1;
    off[4*t+2] = excl + p2;
    off[4*t+3] = excl + p3;
    if (t == 1023) off[4096] = tots[1023];
}

__global__ __launch_bounds__(256)
void segnn_scatter_kernel(const int* __restrict__ rcv, const int* __restrict__ off,
                          int* __restrict__ cursor, int* __restrict__ elist) {
    const int e = blockIdx.x * 256 + threadIdx.x;
    if (e < EDG) {
        const int j = rcv[e];
        const int p = atomicAdd(cursor + j, 1);
        elist[off[j] + p] = e;
    }
}

// ---------------- fused edge pipeline: wave-autonomous, 8 edges/wave ----------------
template<int NSX, int NVX>
__device__ __forceinline__ void edge_phase_w(
    const int lane,
    const float* __restrict__ Ws, const float* __restrict__ Bs,
    const float* __restrict__ Wv,
    float (*xt)[10], float (*x2)[10], float (*cb)[96], float (*cvv)[48])
{
    const int cs = lane & 15, kg = lane >> 4;
    constexpr int KA = NSX + NVX;
    constexpr int CH = KA / 4;

    // ---- pass A ----
    {
        float acc[8][6];
#pragma unroll
        for (int j = 0; j < 8; ++j)
#pragma unroll
            for (int c = 0; c < 6; ++c) acc[j][c] = 0.0f;
        const int r0 = kg * CH;
#pragma unroll 4
        for (int rr = 0; rr < CH; ++rr) {
            const int r = r0 + rr;
            const float* wp = Ws + r*80 + cs;
            const float w0 = wp[0], w1 = wp[16], w2 = wp[32], w3 = wp[48], w4 = wp[64];
            const float w5 = (r < NSX) ? Wv[r*16 + cs] : 0.0f;
            const float2 xa = *reinterpret_cast<const float2*>(&xt[r][0]);
            const float2 xb = *reinterpret_cast<const float2*>(&xt[r][2]);
            const float2 xc = *reinterpret_cast<const float2*>(&xt[r][4]);
            const float2 xd = *reinterpret_cast<const float2*>(&xt[r][6]);
            const float xe[8] = { xa.x,xa.y, xb.x,xb.y, xc.x,xc.y, xd.x,xd.y };
#pragma unroll
            for (int j = 0; j < 8; ++j) {
                acc[j][0] = fmaf(xe[j], w0, acc[j][0]);
                acc[j][1] = fmaf(xe[j], w1, acc[j][1]);
                acc[j][2] = fmaf(xe[j], w2, acc[j][2]);
                acc[j][3] = fmaf(xe[j], w3, acc[j][3]);
                acc[j][4] = fmaf(xe[j], w4, acc[j][4]);
                acc[j][5] = fmaf(xe[j], w5, acc[j][5]);
            }
        }
#pragma unroll
        for (int j = 0; j < 8; ++j)
#pragma unroll
            for (int c = 0; c < 6; ++c) {
                float a = acc[j][c];
                a += __shfl_xor(a, 16);
                a += __shfl_xor(a, 32);
                acc[j][c] = a;
            }
        if (lane < 16) {
#pragma unroll
            for (int j = 0; j < 8; ++j) {
#pragma unroll
                for (int c = 0; c < 5; ++c) cb[j][cs + 16*c] = acc[j][c] + Bs[cs + 16*c];
                cb[j][80 + cs] = acc[j][5];
            }
        }
    }

    // ---- pass B (identity-path vector outputs) ----
    {
        constexpr int CHB = NVX / 4;
        float av[8][3];
#pragma unroll
        for (int j = 0; j < 8; ++j) { av[j][0]=0.0f; av[j][1]=0.0f; av[j][2]=0.0f; }
        const int m0 = kg * CHB;
#pragma unroll
        for (int mm = 0; mm < CHB; ++mm) {
            const int m = m0 + mm;
            const float w = Wv[(NSX + m)*16 + cs];
#pragma unroll
            for (int d = 0; d < 3; ++d) {
                const float2 xa = *reinterpret_cast<const float2*>(&x2[d*NVX + m][0]);
                const float2 xb = *reinterpret_cast<const float2*>(&x2[d*NVX + m][2]);
                const float2 xc = *reinterpret_cast<const float2*>(&x2[d*NVX + m][4]);
                const float2 xd = *reinterpret_cast<const float2*>(&x2[d*NVX + m][6]);
                const float xe[8] = { xa.x,xa.y, xb.x,xb.y, xc.x,xc.y, xd.x,xd.y };
#pragma unroll
                for (int j = 0; j < 8; ++j) av[j][d] = fmaf(xe[j], w, av[j][d]);
            }
        }
#pragma unroll
        for (int j = 0; j < 8; ++j)
#pragma unroll
            for (int d = 0; d < 3; ++d) {
                float a = av[j][d];
                a += __shfl_xor(a, 16);
                a += __shfl_xor(a, 32);
                av[j][d] = a;
            }
        if (lane < 16) {
#pragma unroll
            for (int j = 0; j < 8; ++j)
#pragma unroll
                for (int d = 0; d < 3; ++d) cvv[j][cs*3 + d] = av[j][d];
        }
    }
    asm volatile("" ::: "memory");
}

__global__ __launch_bounds__(256, 2)
void segnn_edge_fused(const float* __restrict__ cs, const float* __restrict__ cv,
                      const int* __restrict__ snd, const int* __restrict__ rcv,
                      const float* __restrict__ W0s, const float* __restrict__ B0, const float* __restrict__ W0v,
                      const float* __restrict__ W1s, const float* __restrict__ B1, const float* __restrict__ W1v,
                      const float* __restrict__ W2s, const float* __restrict__ B2, const float* __restrict__ W2v,
                      float* __restrict__ msg) {
    __shared__ __align__(16) float XT [4][160][10];
    __shared__ __align__(16) float X2T[4][96][10];
    __shared__ __align__(16) float Cb [4][8][96];
    __shared__ __align__(16) float Cv [4][8][48];
    __shared__ float UU [4][8][4];

    const int tid  = threadIdx.x;
    const int w    = tid >> 6;
    const int lane = tid & 63;
    const int e0   = blockIdx.x * 32 + w * 8;

    float (*xt)[10]  = XT[w];
    float (*x2)[10]  = X2T[w];
    float (*cb)[96]  = Cb[w];
    float (*cvv)[48] = Cv[w];
    float (*uuw)[4]  = UU[w];

#pragma unroll
    for (int it = 0; it < 16; ++it) {
        const int e = it >> 1, half = it & 1;
        const int node = (half ? rcv : snd)[e0 + e];
        xt[half*64 + lane][e] = cs[(size_t)node*64 + lane];
    }
#pragma unroll
    for (int it = 0; it < 16; ++it) {
        const int e = it >> 1, half = it & 1;
        if (lane < 48) {
            const int node = (half ? rcv : snd)[e0 + e];
            const int m = lane / 3, d = lane - 3*m;
            x2[d*32 + half*16 + m][e] = cv[(size_t)node*48 + lane];
        }
    }
    asm volatile("" ::: "memory");
    if (lane < 8) {
        const float rx = x2[0][lane]  - x2[16][lane];
        const float ry = x2[32][lane] - x2[48][lane];
        const float rz = x2[64][lane] - x2[80][lane];
        const float rinv = 1.0f / fmaxf(sqrtf(rx*rx+ry*ry+rz*rz), 1e-9f);
        uuw[lane][0] = rx*rinv; uuw[lane][1] = ry*rinv; uuw[lane][2] = rz*rinv;
    }
    asm volatile("" ::: "memory");
#pragma unroll
    for (int it = 0; it < 4; ++it) {
        const int idx = it*64 + lane;
        const int e = idx >> 5, mm = idx & 31;
        xt[128 + mm][e] = x2[mm][e]*uuw[e][0] + x2[32+mm][e]*uuw[e][1] + x2[64+mm][e]*uuw[e][2];
    }
    asm volatile("" ::: "memory");

    // ---- phase 0 ----
    edge_phase_w<128,32>(lane, W0s, B0, W0v, xt, x2, cb, cvv);
#pragma unroll
    for (int it = 0; it < 8; ++it) {
        xt[lane][it] = gelu_f(cb[it][lane]);
    }
#pragma unroll
    for (int it = 0; it < 2; ++it) {
        const int idx = it*64 + lane;
        const int e = idx >> 4, o = idx & 15;
        const float g = sigmoid_f(cb[e][64+o]);
        const float t = cb[e][80+o] * SQRT3;
        float p = 0.0f;
#pragma unroll
        for (int d = 0; d < 3; ++d) {
            const float vd = fmaf(t, uuw[e][d], cvv[e][o*3+d]) * g;
            x2[d*16 + o][e] = vd;
            p = fmaf(vd, uuw[e][d], p);
        }
        xt[64 + o][e] = p;
    }
    asm volatile("" ::: "memory");

    // ---- phase 1 ----
    edge_phase_w<64,16>(lane, W1s, B1, W1v, xt, x2, cb, cvv);
#pragma unroll
    for (int it = 0; it < 8; ++it) {
        xt[lane][it] = gelu_f(cb[it][lane]);
    }
#pragma unroll
    for (int it = 0; it < 2; ++it) {
        const int idx = it*64 + lane;
        const int e = idx >> 4, o = idx & 15;
        const float g = sigmoid_f(cb[e][64+o]);
        const float t = cb[e][80+o] * SQRT3;
        float p = 0.0f;
#pragma unroll
        for (int d = 0; d < 3; ++d) {
            const float vd = fmaf(t, uuw[e][d], cvv[e][o*3+d]) * g;
            x2[d*16 + o][e] = vd;
            p = fmaf(vd, uuw[e][d], p);
        }
        xt[64 + o][e] = p;
    }
    asm volatile("" ::: "memory");

    // ---- phase 2 + coalesced message write ----
    edge_phase_w<64,16>(lane, W2s, B2, W2v, xt, x2, cb, cvv);
#pragma unroll
    for (int it = 0; it < 15; ++it) {
        const int idx = it*64 + lane;
        if (idx < 920) {
            const int e = idx / 115, f = idx - 115*e;
            float vv;
            if (f < 64) {
                vv = gelu_f(cb[e][f]);
            } else if (f < 112) {
                const int q = f - 64, o = q / 3, d = q - 3*o;
                const float g = sigmoid_f(cb[e][64+o]);
                vv = fmaf(cb[e][80+o] * SQRT3, uuw[e][d], cvv[e][q]) * g;
            } else {
                vv = uuw[e][f-112];
            }
            msg[(size_t)(e0+e)*116 + f] = vv;
        }
    }
}

// ---------------- gather: CSR segment-mean -> y ----------------
__global__ __launch_bounds__(128)
void segnn_gather_kernel(const float* __restrict__ msg, const int* __restrict__ off,
                         const int* __restrict__ elist,
                         float* __restrict__ y_s, float* __restrict__ y_v) {
    const int n = blockIdx.x, f = threadIdx.x;
    const int o0 = off[n], o1 = off[n+1];
    const int deg = o1 - o0;
    float acc = 0.0f;
    for (int p = o0; p < o1; ++p) {
        const int eid = elist[p];
        if (f < 115) acc += msg[(size_t)eid*116 + f];
    }
    const float inv = NORMI / (float)(deg > 0 ? deg : 1);
    if (f < 64)        y_s[(size_t)n*65 + f] = acc * inv;
    else if (f < 112)  y_v[(size_t)n*51 + (f-64)] = acc * inv;
    else if (f < 115)  y_v[(size_t)n*51 + 48 + (f-112)] = SQRT3 * acc * inv;
    else if (f == 115) y_s[(size_t)n*65 + 64] = deg ? NORMI : 0.0f;
}

// ---------------- node TP-gate: GEMM, on-the-fly X in LDS, XOR-swizzled Xa ----------------
__global__ __launch_bounds__(512, 4)
void segnn_node_kernel(const float* __restrict__ in_s, const float* __restrict__ in_v,
                       const float* __restrict__ y_s, const float* __restrict__ y_v,
                       const float* __restrict__ W,  const float* __restrict__ B,
                       const float* __restrict__ Wv,
                       float* __restrict__ out_s, float* __restrict__ out_v) {
    __shared__ __align__(16) float xsL[8*65];
    __shared__ __align__(16) float ysL[8*65];
    __shared__ __align__(16) float xvL[8*49];
    __shared__ __align__(16) float yvL[8*51];
    __shared__ __align__(16) float Xa[2][3072];
    __shared__ __align__(16) float red[8][16][41];
    __shared__ float finGG[8*16];

    const int tid  = threadIdx.x;
    const int lane = tid & 63;
    const int wv   = tid >> 6;
    const int nb0  = blockIdx.x * 8;

    for (int idx = tid; idx < 8*64; idx += 512) { const int n = idx >> 6, m = idx & 63; xsL[n*65+m] = in_s[(size_t)(nb0+n)*64 + m]; }
    for (int idx = tid; idx < 8*65; idx += 512) { const int n = idx / 65, k = idx - n*65; ysL[n*65+k] = y_s[(size_t)(nb0+n)*65 + k]; }
    for (int idx = tid; idx < 8*48; idx += 512) { const int n = idx / 48, m = idx - n*48; xvL[n*49+m] = in_v[(size_t)(nb0+n)*48 + m]; }
    for (int idx = tid; idx < 8*51; idx += 512) { const int n = idx / 51, m = idx - n*51; yvL[n*51+m] = y_v[(size_t)(nb0+n)*51 + m]; }
    __syncthreads();

    // ================= ss GEMM =================
    {
        const int cs = tid & 15;
        const int rowgrp = tid >> 4;

        float acc[8][5];
#pragma unroll
        for (int n = 0; n < 8; ++n)
#pragma unroll
            for (int c = 0; c < 5; ++c) acc[n][c] = 0.0f;

        // XOR swizzle: float index fi=rl*8+n -> fi ^ ((rl>>5 & 3)<<3); bijective,
        // keeps 8-blocks contiguous; the 4 rowgroups (Δrl=32) land on banks +0/+8/+16/+24.
        auto genS = [&](int t, int b) {
            const int base = t * 128;
#pragma unroll
            for (int ii = 0; ii < 2; ++ii) {
                const int idx = tid + ii*512;
                const int rl = idx >> 3, n = idx & 7;
                const int r = base + rl;
                float val = 0.0f;
                if (r < 4160) {
                    const int m = r / 65, k = r - m*65;
                    val = xsL[n*65+m] * ysL[n*65+k];
                } else if (r < 4432) {
                    const int q = r - 4160;
                    const int m = q / 17, k = q - m*17;
                    val = (xvL[n*49+m*3+0]*yvL[n*51+k*3+0] +
                           xvL[n*49+m*3+1]*yvL[n*51+k*3+1] +
                           xvL[n*49+m*3+2]*yvL[n*51+k*3+2]) * ISQRT3;
                }
                Xa[b][idx ^ (((idx >> 8) & 3) << 3)] = val;
            }
        };

        genS(0, 0);
        __syncthreads();
        for (int t = 0; t < 35; ++t) {
            if (t + 1 < 35) genS(t + 1, (t + 1) & 1);
            const int base = t * 128;
            const float* Xb = &Xa[t & 1][0];
#pragma unroll
            for (int v2 = 0; v2 < 4; ++v2) {
                const int rl = rowgrp + 32*v2;
                const int r  = base + rl;
                const int wr = r < 4431 ? r : 4431;
                const float* wp = W + (size_t)wr * 80 + cs;
                const float w0 = wp[0], w1 = wp[16], w2 = wp[32], w3 = wp[48], w4_ = wp[64];
                const int sb = (rl*8) ^ (((rl >> 5) & 3) << 3);
                const float4 xq0 = *reinterpret_cast<const float4*>(&Xb[sb]);
                const float4 xq1 = *reinterpret_cast<const float4*>(&Xb[sb+4]);
                const float xn[8] = { xq0.x, xq0.y, xq0.z, xq0.w, xq1.x, xq1.y, xq1.z, xq1.w };
#pragma unroll
                for (int n = 0; n < 8; ++n) {
                    acc[n][0] = fmaf(xn[n], w0,  acc[n][0]);
                    acc[n][1] = fmaf(xn[n], w1,  acc[n][1]);
                    acc[n][2] = fmaf(xn[n], w2,  acc[n][2]);
                    acc[n][3] = fmaf(xn[n], w3,  acc[n][3]);
                    acc[n][4] = fmaf(xn[n], w4_, acc[n][4]);
                }
            }
            __syncthreads();
        }

#pragma unroll
        for (int n = 0; n < 8; ++n)
#pragma unroll
            for (int c = 0; c < 5; ++c) {
                float a = acc[n][c];
                a += __shfl_xor(a, 16);
                a += __shfl_xor(a, 32);
                if (lane < 16) red[wv][lane][n*5+c] = a;
            }
        __syncthreads();
        for (int idx = tid; idx < 8*80; idx += 512) {
            const int n = idx / 80, col = idx - n*80;
            const int cs2 = col & 15, ci2 = col >> 4;
            float s = B[col];
#pragma unroll
            for (int ww = 0; ww < 8; ++ww) s += red[ww][cs2][n*5+ci2];
            if (col < 64) out_s[(size_t)(nb0+n)*64 + col] = gelu_f(s);
            else          finGG[n*16 + (col-64)] = s;
        }
        __syncthreads();
    }

    // ================= vec GEMM =================
    {
        const int j4 = tid & 3;
        const int ngrp = (tid >> 2) & 1;
        const int rg = tid >> 3;

        float av[12][4];
#pragma unroll
        for (int a = 0; a < 12; ++a)
#pragma unroll
            for (int c = 0; c < 4; ++c) av[a][c] = 0.0f;

        auto genV = [&](int t, int b) {
            const int base = t * 128;
#pragma unroll
            for (int ii = 0; ii < 6; ++ii) {
                const int idx = tid + ii*512;
                const int rl = idx / 24, ar = idx - rl*24;
                const int n = ar / 3, d = ar - n*3;
                const int r = base + rl;
                float val = 0.0f;
                if (r < 1088) {
                    const int m = r / 17, k = r - m*17;
                    val = xsL[n*65+m] * yvL[n*51+k*3+d];
                } else if (r < 2128) {
                    const int q = r - 1088;
                    const int m = q / 65, k = q - m*65;
                    val = xvL[n*49+m*3+d] * ysL[n*65+k];
                }
                Xa[b][idx] = val;
            }
        };

        genV(0, 0);
        __syncthreads();
        for (int t = 0; t < 17; ++t) {
            if (t + 1 < 17) genV(t + 1, (t + 1) & 1);
            const float* Xb = &Xa[t & 1][0];
#pragma unroll
            for (int v2 = 0; v2 < 2; ++v2) {
                const int rl = rg + 64*v2;
                const int r  = t*128 + rl;
                const int wr = r < 2127 ? r : 2127;
                const float4 w4 = *reinterpret_cast<const float4*>(&Wv[(size_t)wr*16 + 4*j4]);
                const float4 xq0 = *reinterpret_cast<const float4*>(&Xb[rl*24 + 12*ngrp]);
                const float4 xq1 = *reinterpret_cast<const float4*>(&Xb[rl*24 + 12*ngrp + 4]);
                const float4 xq2 = *reinterpret_cast<const float4*>(&Xb[rl*24 + 12*ngrp + 8]);
                const float xr[12] = { xq0.x,xq0.y,xq0.z,xq0.w, xq1.x,xq1.y,xq1.z,xq1.w, xq2.x,xq2.y,xq2.z,xq2.w };
#pragma unroll
                for (int a = 0; a < 12; ++a) {
                    av[a][0] = fmaf(xr[a], w4.x, av[a][0]);
                    av[a][1] = fmaf(xr[a], w4.y, av[a][1]);
                    av[a][2] = fmaf(xr[a], w4.z, av[a][2]);
                    av[a][3] = fmaf(xr[a], w4.w, av[a][3]);
                }
            }
            __syncthreads();
        }

        float* redf = &red[0][0][0];
#pragma unroll
        for (int a = 0; a < 12; ++a)
#pragma unroll
            for (int c = 0; c < 4; ++c) {
                float x = av[a][c];
                x += __shfl_xor(x, 8);
                x += __shfl_xor(x, 16);
                x += __shfl_xor(x, 32);
                if (lane < 8) redf[wv*392 + lane*49 + a*4 + c] = x;
            }
        __syncthreads();
        for (int idx = tid; idx < 24*16; idx += 512) {
            const int ar = idx >> 4, j = idx & 15;
            const int n = ar / 3, d = ar - n*3;
            const int ng2 = ar / 12, a2 = ar - 12*ng2;
            const int jj4 = j >> 2, c2 = j & 3;
            float s = 0.0f;
#pragma unroll
            for (int ww = 0; ww < 8; ++ww) s += redf[ww*392 + (jj4 + 4*ng2)*49 + a2*4 + c2];
            out_v[(size_t)(nb0+n)*48 + j*3 + d] = s * sigmoid_f(finGG[n*16 + j]);
        }
    }
}

// ---------------- per-step final Linear ----------------
__global__ __launch_bounds__(256)
void segnn_linear_kernel(const float* __restrict__ in_s, const float* __restrict__ in_v,
                         const float* __restrict__ lws, const float* __restrict__ lb,
                         const float* __restrict__ lwv,
                         float* __restrict__ out_s, float* __restrict__ out_v,
                         float* __restrict__ out_cat) {
    const int idx = blockIdx.x * 256 + threadIdx.x;
    if (idx >= NND * 112) return;
    const int nidx = idx / 112, f = idx - nidx * 112;
    if (f < 48) {
        const int k = f / 3, d = f - 3*k;
        const float* vp = in_v + (size_t)nidx * 48 + d;
        float acc = 0.0f;
#pragma unroll
        for (int m = 0; m < 16; ++m) acc = fmaf(vp[m*3], lwv[m*16 + k], acc);
        if (out_cat) out_cat[(size_t)nidx*112 + f] = acc;
        else         out_v[(size_t)nidx*48 + f] = acc;
    } else {
        const int o = f - 48;
        const float* sp = in_s + (size_t)nidx * 64;
        float acc = lb[o];
#pragma unroll
        for (int m = 0; m < 64; ++m) acc = fmaf(sp[m], lws[m*64 + o], acc);
        if (out_cat) out_cat[(size_t)nidx*112 + f] = acc;
        else         out_s[(size_t)nidx*64 + o] = acc;
    }
}

// ---------------- host launcher ----------------
extern "C" void kernel_launch(void* const* d_in, const int* in_sizes, int n_in,
                              void* d_out, int out_size, void* d_ws, size_t ws_size,
                              hipStream_t stream) {
    const float* in_s  = (const float*)d_in[0];
    const float* in_v  = (const float*)d_in[1];
    const int*   snd   = (const int*)  d_in[2];
    const int*   rcv   = (const int*)  d_in[3];
    const float* e1_ws = (const float*)d_in[4];
    const float* e1_b  = (const float*)d_in[5];
    const float* e1_wv = (const float*)d_in[6];
    const float* e2_ws = (const float*)d_in[7];
    const float* e2_b  = (const float*)d_in[8];
    const float* e2_wv = (const float*)d_in[9];
    const float* n_ws  = (const float*)d_in[10];
    const float* n_b   = (const float*)d_in[11];
    const float* n_wv  = (const float*)d_in[12];
    const float* l_ws  = (const float*)d_in[13];
    const float* l_b   = (const float*)d_in[14];
    const float* l_wv  = (const float*)d_in[15];

    float* ws    = (float*)d_ws;
    float* cur_s = ws;                           // N*64   = 262144
    float* cur_v = cur_s + 262144;               // N*48   = 196608
    float* nxt_s = cur_v + 196608;               // N*64
    float* nxt_v = nxt_s + 262144;               // N*48
    float* y_s   = nxt_v + 196608;               // N*65   = 266240
    float* y_v   = y_s + 266240;                 // N*51   = 208896
    float* msg   = y_v + 208896;                 // E*116  = 3801088
    int*   deg    = (int*)(msg + 3801088);       // N
    int*   cursor = deg + 4096;                  // N
    int*   off    = cursor + 4096;               // N+1
    int*   elist  = off + 4097;                  // E

    hipMemsetAsync(deg, 0, (size_t)8192 * sizeof(int), stream);
    hipMemcpyAsync(cur_s, in_s, (size_t)262144 * sizeof(float), hipMemcpyDeviceToDevice, stream);
    hipMemcpyAsync(cur_v, in_v, (size_t)196608 * sizeof(float), hipMemcpyDeviceToDevice, stream);
    segnn_deg_kernel<<<EDG/256, 256, 0, stream>>>(rcv, deg);
    segnn_scan_kernel<<<1, 1024, 0, stream>>>(deg, off);
    segnn_scatter_kernel<<<EDG/256, 256, 0, stream>>>(rcv, off, cursor, elist);

    for (int step = 0; step < 3; ++step) {
        segnn_edge_fused<<<EDG/32, 256, 0, stream>>>(cur_s, cur_v, snd, rcv,
            e1_ws + (size_t)step*160*80, e1_b + step*80, e1_wv + (size_t)step*160*16,
            e2_ws + (size_t)(step*2+0)*80*80, e2_b + (step*2+0)*80, e2_wv + (size_t)(step*2+0)*80*16,
            e2_ws + (size_t)(step*2+1)*80*80, e2_b + (step*2+1)*80, e2_wv + (size_t)(step*2+1)*80*16,
            msg);
        segnn_gather_kernel<<<NND, 128, 0, stream>>>(msg, off, elist, y_s, y_v);

        segnn_node_kernel<<<NND/8, 512, 0, stream>>>(cur_s, cur_v, y_s, y_v,
            n_ws + (size_t)(step*3+0)*4432*80, n_b + (step*3+0)*80, n_wv + (size_t)(step*3+0)*2128*16,
            nxt_s, nxt_v);
        segnn_node_kernel<<<NND/8, 512, 0, stream>>>(nxt_s, nxt_v, y_s, y_v,
            n_ws + (size_t)(step*3+1)*4432*80, n_b + (step*3+1)*80, n_wv + (size_t)(step*3+1)*2128*16,
            cur_s, cur_v);
        segnn_node_kernel<<<NND/8, 512, 0, stream>>>(cur_s, cur_v, y_s, y_v,
            n_ws + (size_t)(step*3+2)*4432*80, n_b + (step*3+2)*80, n_wv + (size_t)(step*3+2)*2128*16,
            nxt_s, nxt_v);

        segnn_linear_kernel<<<(NND*112 + 255)/256, 256, 0, stream>>>(nxt_s, nxt_v,
            l_ws + (size_t)step*64*64, l_b + step*64, l_wv + (size_t)step*16*16,
            cur_s, cur_v, (step == 2) ? (float*)d_out : nullptr);
    }
}